// Round 5
// baseline (44.177 us; speedup 1.0000x reference)
//
#include <hip/hip_runtime.h>

#define NPTS 4096
#define DIMP 17                     // DIM+1
#define ROWP 20                     // padded tile/ws row (80 B, 16B-aligned)
#define RROW 21                     // reduction row stride (odd -> no bank conflict)
#define JPB  128                    // j's per block (32 per wave)
#define IPB  128                    // i's per block (2 per lane)
#define NSLAB (NPTS / JPB)          // 32 j-slabs
#define NIB   (NPTS / IPB)          // 32 i-blocks
#define EOFF  (NSLAB * NPTS * ROWP) // float offset of E partials in ws
#define NEP   (NIB * NSLAB)         // 1024 E partials
#define REDF  (384 * RROW)          // reduction floats (3 waves x 128 rows)

typedef float v2f __attribute__((ext_vector_type(2)));
typedef float v4f __attribute__((ext_vector_type(4)));

// Pass 1: grid (NIB, NSLAB), block 256 = 4 waves, 4 blocks/CU.
// Lane owns i1 = i0+lane and i2 = i0+64+lane (2x register blocking): one
// wave-uniform j-row broadcast from LDS feeds 128 pairs, and the two
// independent per-pair chains give ILP=2 inside each wave.
__global__ __launch_bounds__(256, 4) void hydra_pair_kernel(
    const float* __restrict__ h, float* __restrict__ ws,
    float* __restrict__ out, const int use_ws) {
    const int tid   = threadIdx.x;
    const int lane  = tid & 63;
    const int wid   = tid >> 6;
    const int i0    = blockIdx.x * IPB;
    const int i1    = i0 + lane;
    const int i2    = i0 + 64 + lane;
    const int jbase = blockIdx.y * JPB;

    __shared__ __align__(16) float lds[REDF + 16];   // 32.3 KB (tile overlaps)

    // coalesced stage of the 128-j tile (rows padded to ROWP)
    for (int idx = tid; idx < JPB * DIMP; idx += 256) {
        const int j = idx / DIMP;
        const int k = idx - j * DIMP;
        lds[j * ROWP + k] = h[jbase * DIMP + idx];
    }

    // nhi = (t, -s): dot(nhi, hj) = +cosh(d) = m
    float nh1[DIMP], nh2[DIMP];
#pragma unroll
    for (int k = 0; k < DIMP; ++k) nh1[k] = -h[i1 * DIMP + k];
#pragma unroll
    for (int k = 0; k < DIMP; ++k) nh2[k] = -h[i2 * DIMP + k];
    nh1[0] = -nh1[0];
    nh2[0] = -nh2[0];

    __syncthreads();

    float ac1[DIMP], ac2[DIMP];
#pragma unroll
    for (int k = 0; k < DIMP; ++k) { ac1[k] = 0.0f; ac2[k] = 0.0f; }
    float sm1 = 0.0f, sm2 = 0.0f;   // sum_j C*m  (note g = -m)
    float eacc = 0.0f;              // sum_j V (both i's)

    const float* rowp = lds + (wid * 32) * ROWP;
#pragma unroll 2
    for (int jj = 0; jj < 32; ++jj, rowp += ROWP) {
        const v4f a0 = ((const v4f*)rowp)[0];
        const v4f a1 = ((const v4f*)rowp)[1];
        const v4f a2 = ((const v4f*)rowp)[2];
        const v4f a3 = ((const v4f*)rowp)[3];
        const float a16 = rowp[16];
        const float hj[DIMP] = {a0.x, a0.y, a0.z, a0.w, a1.x, a1.y, a1.z, a1.w,
                                a2.x, a2.y, a2.z, a2.w, a3.x, a3.y, a3.z, a3.w, a16};

        // two Lorentz dots, 2-way split chains each
        float p0 = nh1[0] * hj[0], p1 = nh1[1] * hj[1];
        float q0 = nh2[0] * hj[0], q1 = nh2[1] * hj[1];
#pragma unroll
        for (int k = 2; k < 16; k += 2) {
            p0 = fmaf(nh1[k], hj[k], p0);     p1 = fmaf(nh1[k + 1], hj[k + 1], p1);
            q0 = fmaf(nh2[k], hj[k], q0);     q1 = fmaf(nh2[k + 1], hj[k + 1], q1);
        }
        const float m1 = fmaf(nh1[16], a16, p0 + p1);   // cosh(d1)
        const float m2 = fmaf(nh2[16], a16, q0 + q1);   // cosh(d2)

        // pair 1
        const float x1  = m1 - 1.0f;
        const float ss1 = fmaxf(fmaf(m1, m1, -1.0f), 2e-7f);   // sinh^2, clamped
        const float r1  = __builtin_amdgcn_rsqf(ss1);          // 1/sinh
        const float sq1 = ss1 * r1;                            // sinh
        const float w1  = (x1 - sq1) + 1.0f;                   // e^{-d}
        const float d1  = -__logf(w1);
        const float t1  = __builtin_amdgcn_sqrtf(w1);          // e^{-d/2}
        const float u1  = w1 * w1;                             // e^{-2d}
        const float g1  = u1 * __builtin_amdgcn_rcpf(u1 + 6.1442123533e-6f);
        const float K1  = fmaf(0.5f, t1, -2.0f * u1) * g1;
        const float C1  = K1 * d1 * r1;
        // pair 2
        const float x2  = m2 - 1.0f;
        const float ss2 = fmaxf(fmaf(m2, m2, -1.0f), 2e-7f);
        const float r2  = __builtin_amdgcn_rsqf(ss2);
        const float sq2 = ss2 * r2;
        const float w2  = (x2 - sq2) + 1.0f;
        const float d2  = -__logf(w2);
        const float t2  = __builtin_amdgcn_sqrtf(w2);
        const float u2  = w2 * w2;
        const float g2  = u2 * __builtin_amdgcn_rcpf(u2 + 6.1442123533e-6f);
        const float K2  = fmaf(0.5f, t2, -2.0f * u2) * g2;
        const float C2  = K2 * d2 * r2;

        eacc += (t1 - u1) + (t2 - u2);
        sm1 = fmaf(C1, m1, sm1);
        sm2 = fmaf(C2, m2, sm2);
#pragma unroll
        for (int k = 0; k < DIMP; ++k) {
            ac1[k] = fmaf(C1, hj[k], ac1[k]);
            ac2[k] = fmaf(C2, hj[k], ac2[k]);
        }
    }

    // fold (sum C*g)*h_i = (-sm)*h_i ; h_i[0] = nh[0], h_i[k>=1] = -nh[k]
    ac1[0] = fmaf(-sm1, nh1[0], ac1[0]);
    ac2[0] = fmaf(-sm2, nh2[0], ac2[0]);
#pragma unroll
    for (int k = 1; k < DIMP; ++k) {
        ac1[k] = fmaf(sm1, nh1[k], ac1[k]);
        ac2[k] = fmaf(sm2, nh2[k], ac2[k]);
    }

#pragma unroll
    for (int off = 32; off > 0; off >>= 1) eacc += __shfl_xor(eacc, off);

    __syncthreads();   // tile reads done; reuse LDS for cross-wave reduction
    if (wid > 0) {
        float* dA = lds + ((wid - 1) * 64 + lane) * RROW;
        float* dB = lds + ((192 + (wid - 1) * 64 + lane)) * RROW;
#pragma unroll
        for (int k = 0; k < DIMP; ++k) { dA[k] = ac1[k]; dB[k] = ac2[k]; }
        if (lane == 0) lds[REDF + wid] = eacc;
    }
    __syncthreads();

    if (wid == 0) {
        const float esum = eacc + lds[REDF + 1] + lds[REDF + 2] + lds[REDF + 3];
#pragma unroll
        for (int q = 0; q < 3; ++q) {
            const float* sA = lds + (q * 64 + lane) * RROW;
            const float* sB = lds + ((192 + q * 64 + lane)) * RROW;
#pragma unroll
            for (int k = 0; k < DIMP; ++k) { ac1[k] += sA[k]; ac2[k] += sB[k]; }
        }
        if (use_ws) {
            float* w1p = ws + ((size_t)blockIdx.y * NPTS + i1) * ROWP;
            float* w2p = ws + ((size_t)blockIdx.y * NPTS + i2) * ROWP;
#pragma unroll
            for (int k = 0; k < DIMP; ++k) { w1p[k] = ac1[k]; w2p[k] = ac2[k]; }
            if (lane == 0) ws[EOFF + blockIdx.y * NIB + blockIdx.x] = esum;
        } else {
#pragma unroll
            for (int k = 0; k < DIMP; ++k) {
                atomicAdd(&out[i1 * DIMP + k], ac1[k]);
                atomicAdd(&out[i2 * DIMP + k], ac2[k]);
            }
            if (lane == 0) atomicAdd(&out[NPTS * DIMP], esum);
        }
    }
}

// Pass 2: grid 64 blocks x 256. lane -> i (64 per block), wid -> slab quarter.
__global__ __launch_bounds__(256) void hydra_finalize_kernel(
    const float* __restrict__ ws, float* __restrict__ out, const int use_ws) {
    const int tid  = threadIdx.x;
    const int lane = tid & 63;
    const int q    = tid >> 6;
    const int i    = blockIdx.x * 64 + lane;

    __shared__ __align__(16) float red[3 * 64 * RROW + 8];

    float v[DIMP];
#pragma unroll
    for (int k = 0; k < DIMP; ++k) v[k] = 0.0f;

    if (use_ws) {
#pragma unroll
        for (int ssl = 0; ssl < NSLAB / 4; ++ssl) {
            const int s = q * (NSLAB / 4) + ssl;
            const float* row = ws + ((size_t)s * NPTS + i) * ROWP;
            const v4f b0 = ((const v4f*)row)[0];
            const v4f b1 = ((const v4f*)row)[1];
            const v4f b2 = ((const v4f*)row)[2];
            const v4f b3 = ((const v4f*)row)[3];
            v[0]  += b0.x; v[1]  += b0.y; v[2]  += b0.z; v[3]  += b0.w;
            v[4]  += b1.x; v[5]  += b1.y; v[6]  += b1.z; v[7]  += b1.w;
            v[8]  += b2.x; v[9]  += b2.y; v[10] += b2.z; v[11] += b2.w;
            v[12] += b3.x; v[13] += b3.y; v[14] += b3.z; v[15] += b3.w;
            v[16] += row[16];
        }
        if (q > 0) {
            float* dst = red + ((q - 1) * 64 + lane) * RROW;
#pragma unroll
            for (int k = 0; k < DIMP; ++k) dst[k] = v[k];
        }
        __syncthreads();
        if (q == 0) {
#pragma unroll
            for (int qq = 0; qq < 3; ++qq) {
                const float* src = red + (qq * 64 + lane) * RROW;
#pragma unroll
                for (int k = 0; k < DIMP; ++k) v[k] += src[k];
            }
        }
    } else if (q == 0) {
#pragma unroll
        for (int k = 0; k < DIMP; ++k) v[k] = out[i * DIMP + k];
    }

    if (q == 0) {
        float ss = 0.0f;
#pragma unroll
        for (int k = 0; k < DIMP; ++k) ss = fmaf(v[k], v[k], ss);
        const float nrm   = sqrtf(ss);
        const float scale = fminf(6.0f / fmaxf(nrm, 1e-8f), 1.0f);
#pragma unroll
        for (int k = 0; k < DIMP; ++k) out[i * DIMP + k] = v[k] * scale;
    }

    if (blockIdx.x == 0) {
        if (use_ws) {
            float e = 0.0f;
#pragma unroll
            for (int t = 0; t < NEP / 256; ++t) e += ws[EOFF + tid + t * 256];
#pragma unroll
            for (int off = 32; off > 0; off >>= 1) e += __shfl_xor(e, off);
            __shared__ float es[4];
            if (lane == 0) es[q] = e;
            __syncthreads();
            if (tid == 0) out[NPTS * DIMP] = 0.5f * (es[0] + es[1] + es[2] + es[3]);
        } else {
            if (tid == 0) out[NPTS * DIMP] *= 0.5f;
        }
    }
}

extern "C" void kernel_launch(void* const* d_in, const int* in_sizes, int n_in,
                              void* d_out, int out_size, void* d_ws, size_t ws_size,
                              hipStream_t stream) {
    const float* h = (const float*)d_in[0];
    float* out = (float*)d_out;
    float* ws  = (float*)d_ws;

    const size_t need = (size_t)(EOFF + NEP) * sizeof(float);
    const int use_ws = (ws_size >= need) ? 1 : 0;
    if (!use_ws) {
        hipMemsetAsync(d_out, 0, (size_t)out_size * sizeof(float), stream);
    }

    dim3 grid(NIB, NSLAB);
    hydra_pair_kernel<<<grid, 256, 0, stream>>>(h, ws, out, use_ws);
    hydra_finalize_kernel<<<64, 256, 0, stream>>>(ws, out, use_ws);
}

// Round 7
// 39.489 us; speedup vs baseline: 1.1187x; 1.1187x over previous
//
#include <hip/hip_runtime.h>

#define NPTS 4096
#define DIMP 17                     // DIM+1
#define ROWP 20                     // ws row stride (80 B, 16B-aligned)
#define RROW 21                     // LDS reduction row stride (odd -> conflict-free)
#define JPB  128                    // j's per block (32 per wave)
#define NSLAB (NPTS / JPB)          // 32 j-slabs
#define NIB   (NPTS / 64)           // 64 i-blocks
#define EOFF  (NSLAB * NPTS * ROWP) // float offset of E partials in ws
#define NEP   (NIB * NSLAB)        // 2048 E partials
#define REDF  (192 * RROW)          // reduction floats (3 waves x 64 rows)
#define MAXOFF 278460u              // 4095 * 68 bytes (last legal row offset)

typedef float v4f  __attribute__((ext_vector_type(4)));
typedef float v16f __attribute__((ext_vector_type(16)));

// wait for outstanding s_loads (SMEM returns are unordered -> must drain to 0),
// then pin the schedule so no consumer is hoisted above the wait (rule #18)
#define SWAIT() do {                                        \
    asm volatile("s_waitcnt lgkmcnt(0)" ::: "memory");      \
    __builtin_amdgcn_sched_barrier(0);                      \
} while (0)

// issue the 17-float j-row load into SGPRs (scalar pipe, async).
// Separate asm per instruction + "=&s" early-clobber: dest ranges must NOT
// overlap the address pair (this aliasing was the round-6 NaN).
#define SLOAD(B, B16, OFF) do {                                         \
    const char* _p = hb + (OFF);                                        \
    asm volatile("s_load_dwordx16 %0, %1, 0x0"                          \
                 : "=&s"(B) : "s"(_p));                                 \
    asm volatile("s_load_dword %0, %1, 0x40"                            \
                 : "=&s"(B16) : "s"(_p));                               \
} while (0)

// one pair: j-row in SGPRs (B, B16), i-row in VGPRs (nh: time +, space -)
#define PAIR(B, B16) do {                                               \
    float p0 = nh[0] * (B)[0], p1 = nh[1] * (B)[1];                     \
    p0 = fmaf(nh[2],  (B)[2],  p0);  p1 = fmaf(nh[3],  (B)[3],  p1);    \
    p0 = fmaf(nh[4],  (B)[4],  p0);  p1 = fmaf(nh[5],  (B)[5],  p1);    \
    p0 = fmaf(nh[6],  (B)[6],  p0);  p1 = fmaf(nh[7],  (B)[7],  p1);    \
    p0 = fmaf(nh[8],  (B)[8],  p0);  p1 = fmaf(nh[9],  (B)[9],  p1);    \
    p0 = fmaf(nh[10], (B)[10], p0);  p1 = fmaf(nh[11], (B)[11], p1);    \
    p0 = fmaf(nh[12], (B)[12], p0);  p1 = fmaf(nh[13], (B)[13], p1);    \
    p0 = fmaf(nh[14], (B)[14], p0);  p1 = fmaf(nh[15], (B)[15], p1);    \
    const float m  = fmaf(nh[16], (B16), p0 + p1);    /* cosh(d) */     \
    const float ss = fmaxf(fmaf(m, m, -1.0f), 2e-7f); /* sinh^2 */      \
    const float r  = __builtin_amdgcn_rsqf(ss);       /* 1/sinh */      \
    const float sq = ss * r;                          /* sinh */        \
    const float w  = ((m - 1.0f) - sq) + 1.0f;        /* e^{-d} */      \
    const float d  = -__logf(w);                                        \
    const float t  = __builtin_amdgcn_sqrtf(w);       /* e^{-d/2} */    \
    const float u  = w * w;                           /* e^{-2d} */     \
    const float sg = u * __builtin_amdgcn_rcpf(u + 6.1442123533e-6f);   \
    const float K  = fmaf(0.5f, t, -2.0f * u) * sg;                     \
    const float C  = K * d * r;                                         \
    eacc += (t - u);                                                    \
    sm = fmaf(C, m, sm);                                                \
    ac[0]  = fmaf(C, (B)[0],  ac[0]);  ac[1]  = fmaf(C, (B)[1],  ac[1]);\
    ac[2]  = fmaf(C, (B)[2],  ac[2]);  ac[3]  = fmaf(C, (B)[3],  ac[3]);\
    ac[4]  = fmaf(C, (B)[4],  ac[4]);  ac[5]  = fmaf(C, (B)[5],  ac[5]);\
    ac[6]  = fmaf(C, (B)[6],  ac[6]);  ac[7]  = fmaf(C, (B)[7],  ac[7]);\
    ac[8]  = fmaf(C, (B)[8],  ac[8]);  ac[9]  = fmaf(C, (B)[9],  ac[9]);\
    ac[10] = fmaf(C, (B)[10], ac[10]); ac[11] = fmaf(C, (B)[11], ac[11]);\
    ac[12] = fmaf(C, (B)[12], ac[12]); ac[13] = fmaf(C, (B)[13], ac[13]);\
    ac[14] = fmaf(C, (B)[14], ac[14]); ac[15] = fmaf(C, (B)[15], ac[15]);\
    ac[16] = fmaf(C, (B16), ac[16]);                                    \
} while (0)

// Pass 1: grid (NIB, NSLAB) = (64,32), block 256 = 4 waves, single-i per lane.
// j-rows are wave-uniform -> streamed through SGPRs via s_load (scalar pipe);
// no LDS and no syncthreads in the inner loop. 8 waves/SIMD residency.
__global__ __launch_bounds__(256) void hydra_pair_kernel(
    const float* __restrict__ h, float* __restrict__ ws,
    float* __restrict__ out, const int use_ws) {
    const int tid  = threadIdx.x;
    const int lane = tid & 63;
    const int wid  = tid >> 6;
    const int i    = blockIdx.x * 64 + lane;

    __shared__ float lds[REDF + 16];   // reduction only (16.2 KB)

    // i-row: time component positive, space components negated -> dot = +cosh
    float nh[DIMP];
#pragma unroll
    for (int k = 0; k < DIMP; ++k) nh[k] = -h[i * DIMP + k];
    nh[0] = -nh[0];

    float ac[DIMP];
#pragma unroll
    for (int k = 0; k < DIMP; ++k) ac[k] = 0.0f;
    float sm = 0.0f, eacc = 0.0f;

    const char* hb = (const char*)h;
    // wave-uniform byte offset of this wave's first j-row
    const unsigned base_off = (unsigned)__builtin_amdgcn_readfirstlane(
        (int)((blockIdx.y * JPB + wid * 32) * (DIMP * 4)));

    v16f bA, bB; float tA, tB;
    SLOAD(bA, tA, base_off);
    for (int jj = 0; jj < 32; jj += 2) {
        unsigned o1 = base_off + (unsigned)(jj + 1) * 68u;
        unsigned o2 = base_off + (unsigned)(jj + 2) * 68u;
        if (o2 > MAXOFF) o2 = MAXOFF;   // one-past-last prefetch clamp
        SWAIT();                 // bA ready
        SLOAD(bB, tB, o1);       // prefetch next row
        PAIR(bA, tA);            // ~130 cyc of ALU hides the load
        SWAIT();                 // bB ready
        SLOAD(bA, tA, o2);
        PAIR(bB, tB);
    }

    // F_i = ac + (sum C*inn)*h_i ; inn = -m -> coefficient = -sm
    ac[0] = fmaf(-sm, nh[0], ac[0]);
#pragma unroll
    for (int k = 1; k < DIMP; ++k) ac[k] = fmaf(sm, nh[k], ac[k]);

#pragma unroll
    for (int off = 32; off > 0; off >>= 1) eacc += __shfl_xor(eacc, off);

    __syncthreads();
    if (wid > 0) {
        float* dst = lds + ((wid - 1) * 64 + lane) * RROW;
#pragma unroll
        for (int k = 0; k < DIMP; ++k) dst[k] = ac[k];
        if (lane == 0) lds[REDF + wid] = eacc;
    }
    __syncthreads();

    if (wid == 0) {
        const float esum = eacc + lds[REDF + 1] + lds[REDF + 2] + lds[REDF + 3];
#pragma unroll
        for (int q = 0; q < 3; ++q) {
            const float* src = lds + (q * 64 + lane) * RROW;
#pragma unroll
            for (int k = 0; k < DIMP; ++k) ac[k] += src[k];
        }
        if (use_ws) {
            float* dst = ws + ((size_t)blockIdx.y * NPTS + i) * ROWP;
#pragma unroll
            for (int k = 0; k < DIMP; ++k) dst[k] = ac[k];
            if (lane == 0) ws[EOFF + blockIdx.y * NIB + blockIdx.x] = esum;
        } else {
#pragma unroll
            for (int k = 0; k < DIMP; ++k) atomicAdd(&out[i * DIMP + k], ac[k]);
            if (lane == 0) atomicAdd(&out[NPTS * DIMP], esum);
        }
    }
}

// Pass 2: grid 64 blocks x 256. lane -> i (64 per block), wid -> slab quarter.
__global__ __launch_bounds__(256) void hydra_finalize_kernel(
    const float* __restrict__ ws, float* __restrict__ out, const int use_ws) {
    const int tid  = threadIdx.x;
    const int lane = tid & 63;
    const int q    = tid >> 6;
    const int i    = blockIdx.x * 64 + lane;

    __shared__ __align__(16) float red[3 * 64 * RROW + 8];

    float v[DIMP];
#pragma unroll
    for (int k = 0; k < DIMP; ++k) v[k] = 0.0f;

    if (use_ws) {
#pragma unroll
        for (int ssl = 0; ssl < NSLAB / 4; ++ssl) {
            const int s = q * (NSLAB / 4) + ssl;
            const float* row = ws + ((size_t)s * NPTS + i) * ROWP;
            const v4f b0 = ((const v4f*)row)[0];
            const v4f b1 = ((const v4f*)row)[1];
            const v4f b2 = ((const v4f*)row)[2];
            const v4f b3 = ((const v4f*)row)[3];
            v[0]  += b0.x; v[1]  += b0.y; v[2]  += b0.z; v[3]  += b0.w;
            v[4]  += b1.x; v[5]  += b1.y; v[6]  += b1.z; v[7]  += b1.w;
            v[8]  += b2.x; v[9]  += b2.y; v[10] += b2.z; v[11] += b2.w;
            v[12] += b3.x; v[13] += b3.y; v[14] += b3.z; v[15] += b3.w;
            v[16] += row[16];
        }
        if (q > 0) {
            float* dst = red + ((q - 1) * 64 + lane) * RROW;
#pragma unroll
            for (int k = 0; k < DIMP; ++k) dst[k] = v[k];
        }
        __syncthreads();
        if (q == 0) {
#pragma unroll
            for (int qq = 0; qq < 3; ++qq) {
                const float* src = red + (qq * 64 + lane) * RROW;
#pragma unroll
                for (int k = 0; k < DIMP; ++k) v[k] += src[k];
            }
        }
    } else if (q == 0) {
#pragma unroll
        for (int k = 0; k < DIMP; ++k) v[k] = out[i * DIMP + k];
    }

    if (q == 0) {
        float ss = 0.0f;
#pragma unroll
        for (int k = 0; k < DIMP; ++k) ss = fmaf(v[k], v[k], ss);
        const float nrm   = sqrtf(ss);
        const float scale = fminf(6.0f / fmaxf(nrm, 1e-8f), 1.0f);
#pragma unroll
        for (int k = 0; k < DIMP; ++k) out[i * DIMP + k] = v[k] * scale;
    }

    if (blockIdx.x == 0) {
        if (use_ws) {
            float e = 0.0f;
#pragma unroll
            for (int t = 0; t < NEP / 256; ++t) e += ws[EOFF + tid + t * 256];
#pragma unroll
            for (int off = 32; off > 0; off >>= 1) e += __shfl_xor(e, off);
            __shared__ float es[4];
            if (lane == 0) es[q] = e;
            __syncthreads();
            if (tid == 0) out[NPTS * DIMP] = 0.5f * (es[0] + es[1] + es[2] + es[3]);
        } else {
            if (tid == 0) out[NPTS * DIMP] *= 0.5f;
        }
    }
}

extern "C" void kernel_launch(void* const* d_in, const int* in_sizes, int n_in,
                              void* d_out, int out_size, void* d_ws, size_t ws_size,
                              hipStream_t stream) {
    const float* h = (const float*)d_in[0];
    float* out = (float*)d_out;
    float* ws  = (float*)d_ws;

    const size_t need = (size_t)(EOFF + NEP) * sizeof(float);
    const int use_ws = (ws_size >= need) ? 1 : 0;
    if (!use_ws) {
        hipMemsetAsync(d_out, 0, (size_t)out_size * sizeof(float), stream);
    }

    dim3 grid(NIB, NSLAB);
    hydra_pair_kernel<<<grid, 256, 0, stream>>>(h, ws, out, use_ws);
    hydra_finalize_kernel<<<64, 256, 0, stream>>>(ws, out, use_ws);
}